// Round 13
// baseline (55.976 us; speedup 1.0000x reference)
//
#include <hip/hip_runtime.h>
#include <math.h>

#define DM1 63
#define WROW 64
#define RSIZE (DM1*WROW)
#define VSTR 68            // k01 LDS row stride

typedef float f4 __attribute__((ext_vector_type(4)));

// d_ws float offsets
#define OFF_WT  0u                          // f32 W-tail: 512*RSIZE
#define SZ_WT   (512u*RSIZE)
#define OFF_WRO (OFF_WT + SZ_WT)            // shifted W*ro: 512*64
#define SZ_WRO  (512u*64u)
#define OFF_TH  (OFF_WRO + SZ_WRO)          // th vectors: 1024*64
#define SZ_TH   (1024u*64u)
#define OFF_TC  (OFF_TH + SZ_TH)            // per-b consts {th0,nrm,q,bhu}: 1024*4
#define SZ_TC   (1024u*4u)
#define OFF_ZK  (OFF_TC + SZ_TC)            // per-r consts {zeta,kk,v2,-}: 512*4

__device__ __forceinline__ float qreduce(float d) {
    int t = __builtin_amdgcn_mov_dpp(__float_as_int(d), 0xB1, 0xF, 0xF, true);
    d += __int_as_float(t);
    t = __builtin_amdgcn_mov_dpp(__float_as_int(d), 0x4E, 0xF, 0xF, true);
    d += __int_as_float(t);
    return d;
}

// ---------------- K01: gelu + scale + Householder; side-0: head th + per-b
// consts; side-1: W f32 + wro = W*ro + per-r consts. All f32.
#define K1LOAD(V, s) do { const f4* _vp = (const f4*)(vbase + (size_t)(s) * VSTR); \
    V##0 = _vp[0]; V##1 = _vp[1]; V##2 = _vp[2]; V##3 = _vp[3]; } while(0)

#define K1STEP(V) do { \
    f4 q01 = w0*V##0 + w1*V##1; \
    f4 q23 = w2*V##2 + w3*V##3; \
    f4 q = q01 + q23; \
    float d = (q[0] + q[1]) + (q[2] + q[3]); \
    d = qreduce(d); \
    w0 -= d*V##0; w1 -= d*V##1; w2 -= d*V##2; w3 -= d*V##3; } while(0)

__global__ __launch_bounds__(256) void k01_fused(const float* __restrict__ rwh,
                                                 const float* __restrict__ rwt,
                                                 const float* __restrict__ bwh,
                                                 const float* __restrict__ bwt,
                                                 const int* __restrict__ pos,
                                                 const float* __restrict__ emb,
                                                 const float* __restrict__ bh,
                                                 float* __restrict__ wtg,
                                                 float* __restrict__ wrog,
                                                 float* __restrict__ thg,
                                                 float* __restrict__ thcg,
                                                 float* __restrict__ zkg) {
    int rs = blockIdx.x;
    int side = rs >> 9, r = rs & 511;
    const float* rw = (side ? rwt : rwh) + (size_t)r * 3969;
    __shared__ __align__(16) float vv[64 * VSTR];
    __shared__ float sc[64];
    __shared__ float ro_s[64];
    __shared__ int blist[64];
    __shared__ int bcnt;
    int tid = threadIdx.x;
    if (tid == 0) bcnt = 0;

    if (side && tid < 64) {
        int c = tid;
        float rov = (c < 63) ? tanhf(bwt[r * 63 + c]) * 0.015625f : 0.f;
        ro_s[c] = rov;
        float p = rov * rov;
        #pragma unroll
        for (int off = 32; off; off >>= 1) p += __shfl_xor(p, off);
        if (c == 0) {
            float v2 = p;
            float zeta = 1.f / (sqrtf(1.f - v2) + 1e-8f);
            zkg[r * 4]     = zeta;
            zkg[r * 4 + 1] = (zeta - 1.f) / (v2 + 1e-9f);
            zkg[r * 4 + 2] = v2;
        }
    }

    for (int idx = tid; idx < 3969; idx += 256) {
        int s = idx / 63, j = idx - s * 63;
        float x = rw[idx];
        vv[s * VSTR + j] = 0.5f * x * (1.f + erff(x * 0.70710678118654752f));
    }
    if (tid < DM1) vv[tid * VSTR + 63] = 0.f;
    __syncthreads();

    if (tid < 252) {
        int s = tid >> 2, p = tid & 3;
        const float* vr = &vv[s * VSTR + p * 16];
        float sum = 0.f;
        #pragma unroll
        for (int j = 0; j < 16; j++) { float v = vr[j]; sum = fmaf(v, v, sum); }
        sum = qreduce(sum);
        if (p == 0) sc[s] = sqrtf(2.f / sum);
    }
    __syncthreads();

    for (int idx = tid; idx < DM1 * 64; idx += 256) {
        int s = idx >> 6, j = idx & 63;
        vv[s * VSTR + j] *= sc[s];
    }
    __syncthreads();

    int lane = tid & 63, wv = tid >> 6;
    int row = wv * 16 + (lane >> 2);
    int p = lane & 3;
    int c0 = p * 16;
    const float* vbase = &vv[c0];

    f4 w0, w1, w2, w3;
    #define IW(k, b) (((b) + (k)) == row ? 1.f : 0.f)
    w0 = (f4){IW(0,c0),    IW(1,c0),    IW(2,c0),    IW(3,c0)};
    w1 = (f4){IW(0,c0+4),  IW(1,c0+4),  IW(2,c0+4),  IW(3,c0+4)};
    w2 = (f4){IW(0,c0+8),  IW(1,c0+8),  IW(2,c0+8),  IW(3,c0+8)};
    w3 = (f4){IW(0,c0+12), IW(1,c0+12), IW(2,c0+12), IW(3,c0+12)};
    #undef IW

    f4 va0,va1,va2,va3, vb0,vb1,vb2,vb3, vc0,vc1,vc2,vc3, vd0,vd1,vd2,vd3;
    K1LOAD(va, 0); K1LOAD(vb, 1); K1LOAD(vc, 2); K1LOAD(vd, 3);
    #pragma unroll 1
    for (int s = 0; s < 56; s += 4) {
        K1STEP(va); K1LOAD(va, s + 4);
        K1STEP(vb); K1LOAD(vb, s + 5);
        K1STEP(vc); K1LOAD(vc, s + 6);
        K1STEP(vd); K1LOAD(vd, s + 7);
    }
    K1STEP(va); K1LOAD(va, 60);
    K1STEP(vb); K1LOAD(vb, 61);
    K1STEP(vc); K1LOAD(vc, 62);
    K1STEP(vd);
    K1STEP(va);
    K1STEP(vb);
    K1STEP(vc);

    if (side == 0) {
        // dump W rows to LDS; per-b head transform + consts
        __syncthreads();
        {
            f4* vr = (f4*)&vv[row * VSTR + c0];
            vr[0] = w0; vr[1] = w1; vr[2] = w2; vr[3] = w3;   // row 63 dummy
        }
        __syncthreads();
        for (int i = tid; i < 1024; i += 256)
            if (pos[3 * i + 1] == r) { int s = atomicAdd(&bcnt, 1); if (s < 64) blist[s] = i; }
        __syncthreads();
        int cnt = bcnt < 64 ? bcnt : 64;
        if (cnt) {
            int c = lane;
            float rovh = (c < 63) ? tanhf(bwh[r * 63 + c]) * 0.015625f : 0.f;
            float rovt = (c < 63) ? tanhf(bwt[r * 63 + c]) * 0.015625f : 0.f;
            float pp = rovh * rovh;
            #pragma unroll
            for (int off = 32; off; off >>= 1) pp += __shfl_xor(pp, off);
            float v2 = pp;
            float zeta = 1.f / (sqrtf(1.f - v2) + 1e-8f);
            float kz = (zeta - 1.f) / (v2 + 1e-9f);
            for (int e = wv; e < cnt; e += 4) {
                int b = blist[e];
                int u = pos[3 * b];
                const float* hrow = emb + (size_t)u * 64;   // wave-uniform
                float xnc = 0.f;
                for (int d = 0; d < DM1; d++) xnc = fmaf(hrow[1 + d], vv[d * VSTR + c], xnc);
                float q = xnc * rovh;
                #pragma unroll
                for (int off = 32; off; off >>= 1) q += __shfl_xor(q, off);
                float dot = q;
                float x0 = hrow[0];
                float val; int idx;
                if (c < 63) { val = fmaf(-zeta * x0, rovh, xnc) + kz * rovh * dot; idx = c + 1; }
                else        { val = zeta * x0 - zeta * dot;                         idx = 0;    }
                thg[b * 64 + idx] = val;
                float nn = (c < 63) ? val * val  : 0.f;
                float qq = (c < 63) ? val * rovt : 0.f;
                #pragma unroll
                for (int off = 32; off; off >>= 1) { nn += __shfl_xor(nn, off); qq += __shfl_xor(qq, off); }
                if (c == 63) thcg[b * 4] = val;            // th0
                if (c == 0) {
                    thcg[b * 4 + 1] = nn;                  // ||th1:||^2
                    thcg[b * 4 + 2] = qq;                  // <ro_t, th1:>
                    thcg[b * 4 + 3] = tanhf(bh[u]);        // bhu
                }
            }
        }
    } else {
        // tail side: W f32 from regs + wro = W*ro (shifted by 1)
        if (row < DM1) {
            f4* wo = (f4*)(wtg + (size_t)r * RSIZE + (size_t)row * WROW + c0);
            wo[0] = w0; wo[1] = w1; wo[2] = w2; wo[3] = w3;
        }
        const f4* rp = (const f4*)&ro_s[c0];
        f4 a = w0 * rp[0] + w1 * rp[1] + w2 * rp[2] + w3 * rp[3];
        float pr = (a[0] + a[1]) + (a[2] + a[3]);
        pr = qreduce(pr);                                  // sum over p (quad)
        if (p == 0 && row < DM1) wrog[r * 64 + 1 + row] = pr;
        if (tid == 1) wrog[r * 64] = 0.f;
    }
}

// ---------------- K3: pure-gather scoring. Per candidate: 3 dots (63-d) + scalars.
// score = 0.85 - mkv + bhu + tanh(bt[v]);  mkv = -d0^2 + s3 + A(2(s1-q)+A*v2)
//         + nrm - 2*s2;  s1=<t1:,wro>, s2=<t1:,wth>, s3=||t1:||^2 (W orthogonal).
__global__ __launch_bounds__(256) void k3_score(
    const int* __restrict__ pos, const int* __restrict__ neg,
    const float* __restrict__ emb, const float* __restrict__ bt,
    const float* __restrict__ wtg, const float* __restrict__ wrog,
    const float* __restrict__ thg, const float* __restrict__ thcg,
    const float* __restrict__ zkg, float* __restrict__ out) {
    __shared__ __align__(16) float wro_s[64];
    __shared__ __align__(16) float wth_s[64];
    __shared__ __align__(16) float th_s[64];   // th[1+c], c=0..62; [63]=0
    __shared__ float cst[7];

    int b = blockIdx.x, j = threadIdx.x;
    int r = pos[b * 3 + 1];
    int v = (j == 0) ? pos[b * 3 + 2] : neg[b * 255 + j - 1];

    // issue the random-row gather first
    const f4* tp4 = (const f4*)(emb + (size_t)v * 64);
    f4 trow[16];
    #pragma unroll
    for (int i = 0; i < 16; i++) trow[i] = tp4[i];
    float btraw = bt[v];

    if (j < 16)            ((f4*)wro_s)[j] = ((const f4*)(wrog + r * 64))[j];
    else if (j == 32)      { cst[0] = zkg[r * 4]; cst[1] = zkg[r * 4 + 1]; cst[2] = zkg[r * 4 + 2]; }
    else if (j == 33)      { const float* tc = thcg + b * 4;
                             cst[3] = tc[0]; cst[4] = tc[1]; cst[5] = tc[2]; cst[6] = tc[3]; }
    else if (j >= 64 && j < 128) { int c = j - 64; th_s[c] = (c < 63) ? thg[b * 64 + 1 + c] : 0.f; }
    __syncthreads();

    // wth = W*th1: (shifted). thread (d=j>>2, p=j&3): 16-col partial, quad-reduce.
    {
        int d = j >> 2, p = j & 3;
        const f4* wrow = (const f4*)(wtg + (size_t)r * RSIZE + (size_t)d * 64 + p * 16);
        const f4* ts4 = (const f4*)&th_s[p * 16];
        f4 a = wrow[0] * ts4[0] + wrow[1] * ts4[1] + wrow[2] * ts4[2] + wrow[3] * ts4[3];
        float pr = (a[0] + a[1]) + (a[2] + a[3]);
        pr = qreduce(pr);
        if (p == 0 && d < 63) wth_s[1 + d] = pr;
        if (j == 252) wth_s[0] = 0.f;               // d=63 quad writes the shift-pad
    }
    __syncthreads();

    // main: 3 dots + scalar math
    float x0 = trow[0][0];
    const f4* wr4 = (const f4*)wro_s;
    const f4* wt4 = (const f4*)wth_s;
    f4 a1 = (f4)0.f, a2 = (f4)0.f, a3 = (f4)0.f;
    #pragma unroll
    for (int i = 0; i < 16; i++) {
        f4 t = trow[i];
        a3 += t * t;
        a1 += t * wr4[i];
        a2 += t * wt4[i];
    }
    float s3 = (a3[0] + a3[1]) + (a3[2] + a3[3]) - x0 * x0;
    float s1 = (a1[0] + a1[1]) + (a1[2] + a1[3]);
    float s2 = (a2[0] + a2[1]) + (a2[2] + a2[3]);
    float zeta = cst[0], kk = cst[1], v2 = cst[2];
    float th0 = cst[3], nrm = cst[4], q = cst[5], bhu = cst[6];
    float A  = fmaf(kk, s1, -zeta * x0);
    float d0 = fmaf(zeta, x0 - s1, -th0);
    float m1 = s3 + nrm - 2.f * s2 + A * (2.f * (s1 - q) + A * v2);
    float mkv = m1 - d0 * d0;
    out[b * 256 + j] = 0.85f - mkv + bhu + tanhf(btraw);
}

extern "C" void kernel_launch(void* const* d_in, const int* in_sizes, int n_in,
                              void* d_out, int out_size, void* d_ws, size_t ws_size,
                              hipStream_t stream) {
    const int*   pos = (const int*)d_in[0];
    const int*   neg = (const int*)d_in[1];
    const float* emb = (const float*)d_in[2];
    const float* bh  = (const float*)d_in[3];
    const float* bt  = (const float*)d_in[4];
    const float* rwh = (const float*)d_in[5];
    const float* bwh = (const float*)d_in[6];
    const float* rwt = (const float*)d_in[7];
    const float* bwt = (const float*)d_in[8];
    float* ws   = (float*)d_ws;
    float* wtg  = ws + OFF_WT;
    float* wrog = ws + OFF_WRO;
    float* thg  = ws + OFF_TH;
    float* thcg = ws + OFF_TC;
    float* zkg  = ws + OFF_ZK;
    float* out  = (float*)d_out;

    k01_fused<<<dim3(1024), dim3(256), 0, stream>>>(rwh, rwt, bwh, bwt, pos, emb,
                                                    bh, wtg, wrog, thg, thcg, zkg);
    k3_score <<<dim3(1024), dim3(256), 0, stream>>>(pos, neg, emb, bt, wtg, wrog,
                                                    thg, thcg, zkg, out);
}

// Round 14
// 53.424 us; speedup vs baseline: 1.0478x; 1.0478x over previous
//
#include <hip/hip_runtime.h>
#include <math.h>

#define DM1 63
#define VSTR 68            // LDS row stride for v-vectors

typedef float f4 __attribute__((ext_vector_type(4)));

// d_ws float offsets
#define OFF_WRO 0u                          // shifted W_t*ro: 512*64
#define SZ_WRO  (512u*64u)
#define OFF_WTH (OFF_WRO + SZ_WRO)          // shifted W_t*th1: 1024*64
#define SZ_WTH  (1024u*64u)
#define OFF_TC  (OFF_WTH + SZ_WTH)          // per-b consts {th0,nrm,q,bhu}: 1024*4
#define SZ_TC   (1024u*4u)
#define OFF_ZK  (OFF_TC + SZ_TC)            // per-r consts {zeta,kk,v2,-}: 512*4

__device__ __forceinline__ float qreduce(float d) {   // 4-lane quad sum
    int t = __builtin_amdgcn_mov_dpp(__float_as_int(d), 0xB1, 0xF, 0xF, true);
    d += __int_as_float(t);
    t = __builtin_amdgcn_mov_dpp(__float_as_int(d), 0x4E, 0xF, 0xF, true);
    d += __int_as_float(t);
    return d;
}

// 64-lane sum via DPP row_shr/row_bcast ladder; uniform result via readlane(63).
__device__ __forceinline__ float wred(float x) {
    float s = x;
#define ST(ctrl, rmask) s += __int_as_float(__builtin_amdgcn_update_dpp( \
        0, __float_as_int(s), ctrl, rmask, 0xF, true))
    ST(0x111, 0xF);   // row_shr:1
    ST(0x112, 0xF);   // row_shr:2
    ST(0x114, 0xF);   // row_shr:4
    ST(0x118, 0xF);   // row_shr:8
    ST(0x142, 0xA);   // row_bcast:15 -> rows 1,3
    ST(0x143, 0xC);   // row_bcast:31 -> rows 2,3
#undef ST
    return __int_as_float(__builtin_amdgcn_readlane(__float_as_int(s), 63));
}

// ---------------- K_prep: one block per relation. gelu both sides into LDS,
// then ONLY matrix-vector Householder applications (no W materialization):
//   xn = h1^T W_h (ascending), th=boost_h(xn); wth = W_t*th1 (descending);
//   wro = W_t*ro_t (descending). Plus all scalar consts.
__global__ __launch_bounds__(256) void k_prep(const float* __restrict__ rwh,
                                              const float* __restrict__ rwt,
                                              const float* __restrict__ bwh,
                                              const float* __restrict__ bwt,
                                              const int* __restrict__ pos,
                                              const float* __restrict__ emb,
                                              const float* __restrict__ bh,
                                              float* __restrict__ wrog,
                                              float* __restrict__ wthg,
                                              float* __restrict__ thcg,
                                              float* __restrict__ zkg) {
    int r = blockIdx.x;                  // 0..511
    __shared__ __align__(16) float vvh[DM1 * VSTR];
    __shared__ __align__(16) float vvt[DM1 * VSTR];
    __shared__ float sch[64], sct[64];
    __shared__ float rovh_s[64], rovt_s[64];
    __shared__ float hcons[2];           // zeta_h, kz_h
    __shared__ int blist[64];
    __shared__ int bcnt;
    int tid = threadIdx.x;
    if (tid == 0) bcnt = 0;

    // gelu both sides
    const float* rwhr = rwh + (size_t)r * 3969;
    const float* rwtr = rwt + (size_t)r * 3969;
    for (int idx = tid; idx < 3969; idx += 256) {
        int s = idx / 63, j = idx - s * 63;
        float xh = rwhr[idx], xt = rwtr[idx];
        vvh[s * VSTR + j] = 0.5f * xh * (1.f + erff(xh * 0.70710678118654752f));
        vvt[s * VSTR + j] = 0.5f * xt * (1.f + erff(xt * 0.70710678118654752f));
    }
    if (tid < DM1) { vvh[tid * VSTR + 63] = 0.f; vvt[tid * VSTR + 63] = 0.f; }

    // boost vectors + consts (independent of vv)
    if (tid < 64) {
        int c = tid;
        float rov = (c < 63) ? tanhf(bwh[r * 63 + c]) * 0.015625f : 0.f;
        rovh_s[c] = rov;
        float p = rov * rov;
        #pragma unroll
        for (int off = 32; off; off >>= 1) p += __shfl_xor(p, off);
        if (c == 0) {
            float v2 = p;
            float zeta = 1.f / (sqrtf(1.f - v2) + 1e-8f);
            hcons[0] = zeta;
            hcons[1] = (zeta - 1.f) / (v2 + 1e-9f);
        }
    } else if (tid < 128) {
        int c = tid - 64;
        float rov = (c < 63) ? tanhf(bwt[r * 63 + c]) * 0.015625f : 0.f;
        rovt_s[c] = rov;
        float p = rov * rov;
        #pragma unroll
        for (int off = 32; off; off >>= 1) p += __shfl_xor(p, off);
        if (c == 0) {
            float v2 = p;
            float zeta = 1.f / (sqrtf(1.f - v2) + 1e-8f);
            zkg[r * 4]     = zeta;
            zkg[r * 4 + 1] = (zeta - 1.f) / (v2 + 1e-9f);
            zkg[r * 4 + 2] = v2;
        }
    }
    __syncthreads();

    // per-step scales sqrt(2/||v||^2), both sides; + scan pos for our b's
    if (tid < 252) {
        int s = tid >> 2, p = tid & 3;
        const float* vr = &vvh[s * VSTR + p * 16];
        float sum = 0.f;
        #pragma unroll
        for (int j = 0; j < 16; j++) { float v = vr[j]; sum = fmaf(v, v, sum); }
        sum = qreduce(sum);
        if (p == 0) sch[s] = sqrtf(2.f / sum);
        const float* vr2 = &vvt[s * VSTR + p * 16];
        float sum2 = 0.f;
        #pragma unroll
        for (int j = 0; j < 16; j++) { float v = vr2[j]; sum2 = fmaf(v, v, sum2); }
        sum2 = qreduce(sum2);
        if (p == 0) sct[s] = sqrtf(2.f / sum2);
    }
    for (int i = tid; i < 1024; i += 256)
        if (pos[3 * i + 1] == r) { int s = atomicAdd(&bcnt, 1); if (s < 64) blist[s] = i; }
    __syncthreads();

    for (int idx = tid; idx < DM1 * 64; idx += 256) {
        int s = idx >> 6, j = idx & 63;
        vvh[s * VSTR + j] *= sch[s];
        vvt[s * VSTR + j] *= sct[s];
    }
    __syncthreads();

    int lane = tid & 63, wv = tid >> 6;
    int cnt = bcnt < 64 ? bcnt : 64;
    float zeta_h = hcons[0], kz_h = hcons[1];

    if (wv == 0) {
        // wro = W_t * ro_t  (descending), one-ahead LDS prefetch
        float y = rovt_s[lane];
        float vs = vvt[62 * VSTR + lane];
        #pragma unroll 7
        for (int s = 62; s >= 0; s--) {
            float vn = (s > 0) ? vvt[(s - 1) * VSTR + lane] : 0.f;
            float dot = wred(y * vs);
            y = fmaf(-dot, vs, y);
            vs = vn;
        }
        if (lane < 63) wrog[r * 64 + 1 + lane] = y;
        else           wrog[r * 64] = 0.f;
    } else {
        for (int e = wv - 1; e < cnt; e += 3) {
            int b = blist[e];
            int u = pos[3 * b];
            const float* hrow = emb + (size_t)u * 64;
            float x0 = hrow[0];
            float y = (lane < 63) ? hrow[1 + lane] : 0.f;
            // xn = h1^T W_h : ascending
            float vs = vvh[0 * VSTR + lane];
            #pragma unroll 7
            for (int s = 0; s < 63; s++) {
                float vn = (s < 62) ? vvh[(s + 1) * VSTR + lane] : 0.f;
                float dot = wred(y * vs);
                y = fmaf(-dot, vs, y);
                vs = vn;
            }
            // boost head
            float rh = rovh_s[lane];
            float dot = wred(y * rh);
            float th1 = (lane < 63) ? fmaf(-zeta_h * x0, rh, y) + kz_h * rh * dot : 0.f;
            float th0 = zeta_h * x0 - zeta_h * dot;
            float nn = wred(th1 * th1);
            float qq = wred(th1 * rovt_s[lane]);
            if (lane == 0) {
                thcg[b * 4]     = th0;
                thcg[b * 4 + 1] = nn;
                thcg[b * 4 + 2] = qq;
                thcg[b * 4 + 3] = tanhf(bh[u]);
            }
            // wth = W_t * th1 : descending
            float z = th1;
            float ws2 = vvt[62 * VSTR + lane];
            #pragma unroll 7
            for (int s = 62; s >= 0; s--) {
                float wn = (s > 0) ? vvt[(s - 1) * VSTR + lane] : 0.f;
                float d2 = wred(z * ws2);
                z = fmaf(-d2, ws2, z);
                ws2 = wn;
            }
            if (lane < 63) wthg[b * 64 + 1 + lane] = z;
            else           wthg[b * 64] = 0.f;
        }
    }
}

// ---------------- K3: pure-gather scoring. Per candidate: 3 dots + scalars.
// score = 0.85 - mkv + bhu + tanh(bt[v]);  mkv = -d0^2 + s3 + nrm - 2*s2
//         + A*(2*(s1-q) + A*v2);  s1=<t1,wro>, s2=<t1,wth>, s3=||t1||^2.
__global__ __launch_bounds__(256) void k3_score(
    const int* __restrict__ pos, const int* __restrict__ neg,
    const float* __restrict__ emb, const float* __restrict__ bt,
    const float* __restrict__ wrog, const float* __restrict__ wthg,
    const float* __restrict__ thcg, const float* __restrict__ zkg,
    float* __restrict__ out) {
    __shared__ __align__(16) float wro_s[64];
    __shared__ __align__(16) float wth_s[64];
    __shared__ float cst[7];

    int b = blockIdx.x, j = threadIdx.x;
    int r = pos[b * 3 + 1];
    int v = (j == 0) ? pos[b * 3 + 2] : neg[b * 255 + j - 1];

    // issue the random-row gather first
    const f4* tp4 = (const f4*)(emb + (size_t)v * 64);
    f4 trow[16];
    #pragma unroll
    for (int i = 0; i < 16; i++) trow[i] = tp4[i];
    float btraw = bt[v];

    if (j < 16)            ((f4*)wro_s)[j]      = ((const f4*)(wrog + r * 64))[j];
    else if (j < 32)       ((f4*)wth_s)[j - 16] = ((const f4*)(wthg + b * 64))[j - 16];
    else if (j == 32)      { cst[0] = zkg[r * 4]; cst[1] = zkg[r * 4 + 1]; cst[2] = zkg[r * 4 + 2]; }
    else if (j == 33)      { const float* tc = thcg + b * 4;
                             cst[3] = tc[0]; cst[4] = tc[1]; cst[5] = tc[2]; cst[6] = tc[3]; }
    __syncthreads();

    float x0 = trow[0][0];
    const f4* wr4 = (const f4*)wro_s;
    const f4* wt4 = (const f4*)wth_s;
    f4 a1 = (f4)0.f, a2 = (f4)0.f, a3 = (f4)0.f;
    #pragma unroll
    for (int i = 0; i < 16; i++) {
        f4 t = trow[i];
        a3 += t * t;
        a1 += t * wr4[i];
        a2 += t * wt4[i];
    }
    float s3 = (a3[0] + a3[1]) + (a3[2] + a3[3]) - x0 * x0;
    float s1 = (a1[0] + a1[1]) + (a1[2] + a1[3]);
    float s2 = (a2[0] + a2[1]) + (a2[2] + a2[3]);
    float zeta = cst[0], kk = cst[1], v2 = cst[2];
    float th0 = cst[3], nrm = cst[4], q = cst[5], bhu = cst[6];
    float A  = fmaf(kk, s1, -zeta * x0);
    float d0 = fmaf(zeta, x0 - s1, -th0);
    float m1 = s3 + nrm - 2.f * s2 + A * (2.f * (s1 - q) + A * v2);
    float mkv = m1 - d0 * d0;
    out[b * 256 + j] = 0.85f - mkv + bhu + tanhf(btraw);
}

extern "C" void kernel_launch(void* const* d_in, const int* in_sizes, int n_in,
                              void* d_out, int out_size, void* d_ws, size_t ws_size,
                              hipStream_t stream) {
    const int*   pos = (const int*)d_in[0];
    const int*   neg = (const int*)d_in[1];
    const float* emb = (const float*)d_in[2];
    const float* bh  = (const float*)d_in[3];
    const float* bt  = (const float*)d_in[4];
    const float* rwh = (const float*)d_in[5];
    const float* bwh = (const float*)d_in[6];
    const float* rwt = (const float*)d_in[7];
    const float* bwt = (const float*)d_in[8];
    float* ws   = (float*)d_ws;
    float* wrog = ws + OFF_WRO;
    float* wthg = ws + OFF_WTH;
    float* thcg = ws + OFF_TC;
    float* zkg  = ws + OFF_ZK;
    float* out  = (float*)d_out;

    k_prep  <<<dim3(512),  dim3(256), 0, stream>>>(rwh, rwt, bwh, bwt, pos, emb,
                                                   bh, wrog, wthg, thcg, zkg);
    k3_score<<<dim3(1024), dim3(256), 0, stream>>>(pos, neg, emb, bt, wrog, wthg,
                                                   thcg, zkg, out);
}

// Round 15
// 38.378 us; speedup vs baseline: 1.4586x; 1.3921x over previous
//
#include <hip/hip_runtime.h>
#include <math.h>

#define DM1 63
#define VSTR 68            // LDS row stride for v-vectors

typedef float f4 __attribute__((ext_vector_type(4)));

// d_ws float offsets
#define OFF_WRO 0u                          // shifted W_t*ro: 512*64
#define SZ_WRO  (512u*64u)
#define OFF_WTH (OFF_WRO + SZ_WRO)          // shifted W_t*th1: 1024*64
#define SZ_WTH  (1024u*64u)
#define OFF_TC  (OFF_WTH + SZ_WTH)          // per-b consts {th0,nrm,q,bhu}: 1024*4
#define SZ_TC   (1024u*4u)
#define OFF_ZK  (OFF_TC + SZ_TC)            // per-r consts {zeta,kk,v2,-}: 512*4

__device__ __forceinline__ float qreduce(float d) {   // 4-lane quad sum
    int t = __builtin_amdgcn_mov_dpp(__float_as_int(d), 0xB1, 0xF, 0xF, true);
    d += __int_as_float(t);
    t = __builtin_amdgcn_mov_dpp(__float_as_int(d), 0x4E, 0xF, 0xF, true);
    d += __int_as_float(t);
    return d;
}

__device__ __forceinline__ float qbcast0(float x) {   // broadcast lane 4k -> quad
    return __int_as_float(__builtin_amdgcn_mov_dpp(__float_as_int(x), 0x00, 0xF, 0xF, true));
}

// 64-lane sum via DPP row_shr/row_bcast ladder; uniform result via readlane(63).
__device__ __forceinline__ float wred(float x) {
    float s = x;
#define ST(ctrl, rmask) s += __int_as_float(__builtin_amdgcn_update_dpp( \
        0, __float_as_int(s), ctrl, rmask, 0xF, true))
    ST(0x111, 0xF);   // row_shr:1
    ST(0x112, 0xF);   // row_shr:2
    ST(0x114, 0xF);   // row_shr:4
    ST(0x118, 0xF);   // row_shr:8
    ST(0x142, 0xA);   // row_bcast:15 -> rows 1,3
    ST(0x143, 0xC);   // row_bcast:31 -> rows 2,3
#undef ST
    return __int_as_float(__builtin_amdgcn_readlane(__float_as_int(s), 63));
}

// ---------------- K_prep: one block per relation, 512 threads (8 waves).
// gelu both sides into LDS, then matrix-vector Householder applications only.
__global__ __launch_bounds__(512) void k_prep(const float* __restrict__ rwh,
                                              const float* __restrict__ rwt,
                                              const float* __restrict__ bwh,
                                              const float* __restrict__ bwt,
                                              const int* __restrict__ pos,
                                              const float* __restrict__ emb,
                                              const float* __restrict__ bh,
                                              float* __restrict__ wrog,
                                              float* __restrict__ wthg,
                                              float* __restrict__ thcg,
                                              float* __restrict__ zkg) {
    int r = blockIdx.x;                  // 0..511
    __shared__ __align__(16) float vvh[DM1 * VSTR];
    __shared__ __align__(16) float vvt[DM1 * VSTR];
    __shared__ float sch[64], sct[64];
    __shared__ float rovh_s[64], rovt_s[64];
    __shared__ float hcons[2];           // zeta_h, kz_h
    __shared__ int blist[64];
    __shared__ int bcnt;
    int tid = threadIdx.x;
    if (tid == 0) bcnt = 0;

    // gelu both sides
    const float* rwhr = rwh + (size_t)r * 3969;
    const float* rwtr = rwt + (size_t)r * 3969;
    for (int idx = tid; idx < 3969; idx += 512) {
        int s = idx / 63, j = idx - s * 63;
        float xh = rwhr[idx], xt = rwtr[idx];
        vvh[s * VSTR + j] = 0.5f * xh * (1.f + erff(xh * 0.70710678118654752f));
        vvt[s * VSTR + j] = 0.5f * xt * (1.f + erff(xt * 0.70710678118654752f));
    }
    if (tid < DM1) { vvh[tid * VSTR + 63] = 0.f; vvt[tid * VSTR + 63] = 0.f; }

    // boost vectors + consts (independent of vv)
    if (tid < 64) {
        int c = tid;
        float rov = (c < 63) ? tanhf(bwh[r * 63 + c]) * 0.015625f : 0.f;
        rovh_s[c] = rov;
        float p = rov * rov;
        #pragma unroll
        for (int off = 32; off; off >>= 1) p += __shfl_xor(p, off);
        if (c == 0) {
            float v2 = p;
            float zeta = 1.f / (sqrtf(1.f - v2) + 1e-8f);
            hcons[0] = zeta;
            hcons[1] = (zeta - 1.f) / (v2 + 1e-9f);
        }
    } else if (tid < 128) {
        int c = tid - 64;
        float rov = (c < 63) ? tanhf(bwt[r * 63 + c]) * 0.015625f : 0.f;
        rovt_s[c] = rov;
        float p = rov * rov;
        #pragma unroll
        for (int off = 32; off; off >>= 1) p += __shfl_xor(p, off);
        if (c == 0) {
            float v2 = p;
            float zeta = 1.f / (sqrtf(1.f - v2) + 1e-8f);
            zkg[r * 4]     = zeta;
            zkg[r * 4 + 1] = (zeta - 1.f) / (v2 + 1e-9f);
            zkg[r * 4 + 2] = v2;
        }
    }
    __syncthreads();

    // per-step scales sqrt(2/||v||^2), both sides; + scan pos for our b's
    if (tid < 252) {
        int s = tid >> 2, p = tid & 3;
        const float* vr = &vvh[s * VSTR + p * 16];
        float sum = 0.f;
        #pragma unroll
        for (int j = 0; j < 16; j++) { float v = vr[j]; sum = fmaf(v, v, sum); }
        sum = qreduce(sum);
        if (p == 0) sch[s] = sqrtf(2.f / sum);
        const float* vr2 = &vvt[s * VSTR + p * 16];
        float sum2 = 0.f;
        #pragma unroll
        for (int j = 0; j < 16; j++) { float v = vr2[j]; sum2 = fmaf(v, v, sum2); }
        sum2 = qreduce(sum2);
        if (p == 0) sct[s] = sqrtf(2.f / sum2);
    }
    for (int i = tid; i < 1024; i += 512)
        if (pos[3 * i + 1] == r) { int s = atomicAdd(&bcnt, 1); if (s < 64) blist[s] = i; }
    __syncthreads();

    for (int idx = tid; idx < DM1 * 64; idx += 512) {
        int s = idx >> 6, j = idx & 63;
        vvh[s * VSTR + j] *= sch[s];
        vvt[s * VSTR + j] *= sct[s];
    }
    __syncthreads();

    int lane = tid & 63, wv = tid >> 6;   // wv 0..7
    int cnt = bcnt < 64 ? bcnt : 64;
    float zeta_h = hcons[0], kz_h = hcons[1];

    if (wv == 0) {
        // wro = W_t * ro_t  (descending), one-ahead LDS prefetch
        float y = rovt_s[lane];
        float vs = vvt[62 * VSTR + lane];
        #pragma unroll 7
        for (int s = 62; s >= 0; s--) {
            float vn = (s > 0) ? vvt[(s - 1) * VSTR + lane] : 0.f;
            float dot = wred(y * vs);
            y = fmaf(-dot, vs, y);
            vs = vn;
        }
        if (lane < 63) wrog[r * 64 + 1 + lane] = y;
        else           wrog[r * 64] = 0.f;
    } else {
        for (int e = wv - 1; e < cnt; e += 7) {
            int b = blist[e];
            int u = pos[3 * b];
            const float* hrow = emb + (size_t)u * 64;
            float x0 = hrow[0];
            float y = (lane < 63) ? hrow[1 + lane] : 0.f;
            // xn = h1^T W_h : ascending
            float vs = vvh[0 * VSTR + lane];
            #pragma unroll 7
            for (int s = 0; s < 63; s++) {
                float vn = (s < 62) ? vvh[(s + 1) * VSTR + lane] : 0.f;
                float dot = wred(y * vs);
                y = fmaf(-dot, vs, y);
                vs = vn;
            }
            // boost head
            float rh = rovh_s[lane];
            float dot = wred(y * rh);
            float th1 = (lane < 63) ? fmaf(-zeta_h * x0, rh, y) + kz_h * rh * dot : 0.f;
            float th0 = zeta_h * x0 - zeta_h * dot;
            float nn = wred(th1 * th1);
            float qq = wred(th1 * rovt_s[lane]);
            if (lane == 0) {
                thcg[b * 4]     = th0;
                thcg[b * 4 + 1] = nn;
                thcg[b * 4 + 2] = qq;
                thcg[b * 4 + 3] = tanhf(bh[u]);
            }
            // wth = W_t * th1 : descending
            float z = th1;
            float ws2 = vvt[62 * VSTR + lane];
            #pragma unroll 7
            for (int s = 62; s >= 0; s--) {
                float wn = (s > 0) ? vvt[(s - 1) * VSTR + lane] : 0.f;
                float d2 = wred(z * ws2);
                z = fmaf(-d2, ws2, z);
                ws2 = wn;
            }
            if (lane < 63) wthg[b * 64 + 1 + lane] = z;
            else           wthg[b * 64] = 0.f;
        }
    }
}

// ---------------- K3: quad-cooperative gather scoring. 4 lanes share one
// candidate row (64 B contiguous per lane -> 4x less per-instr divergence).
__global__ __launch_bounds__(256) void k3_score(
    const int* __restrict__ pos, const int* __restrict__ neg,
    const float* __restrict__ emb, const float* __restrict__ bt,
    const float* __restrict__ wrog, const float* __restrict__ wthg,
    const float* __restrict__ thcg, const float* __restrict__ zkg,
    float* __restrict__ out) {
    __shared__ __align__(16) float wro_s[64];
    __shared__ __align__(16) float wth_s[64];
    __shared__ float cst[7];

    int b = blockIdx.x, j = threadIdx.x;
    int r = pos[b * 3 + 1];
    int qslot = j >> 2, p = j & 3;

    if (j < 16)            ((f4*)wro_s)[j]      = ((const f4*)(wrog + r * 64))[j];
    else if (j < 32)       ((f4*)wth_s)[j - 16] = ((const f4*)(wthg + b * 64))[j - 16];
    else if (j == 32)      { cst[0] = zkg[r * 4]; cst[1] = zkg[r * 4 + 1]; cst[2] = zkg[r * 4 + 2]; }
    else if (j == 33)      { const float* tc = thcg + b * 4;
                             cst[3] = tc[0]; cst[4] = tc[1]; cst[5] = tc[2]; cst[6] = tc[3]; }
    __syncthreads();

    float zeta = cst[0], kk = cst[1], v2 = cst[2];
    float th0 = cst[3], nrm = cst[4], qd = cst[5], bhu = cst[6];
    const f4* wr4 = (const f4*)wro_s + p * 4;
    const f4* wt4 = (const f4*)wth_s + p * 4;

    #pragma unroll
    for (int cc = 0; cc < 4; cc++) {
        int cand = cc * 64 + qslot;
        int v = (cand == 0) ? pos[b * 3 + 2] : neg[b * 255 + cand - 1];
        const f4* tp = (const f4*)(emb + (size_t)v * 64) + p * 4;
        f4 t0 = tp[0], t1 = tp[1], t2 = tp[2], t3 = tp[3];
        float btv = bt[v];

        float x0 = qbcast0(t0[0]);                   // element 0 lives in lane p=0
        f4 a1 = t0 * wr4[0] + t1 * wr4[1] + t2 * wr4[2] + t3 * wr4[3];
        f4 a2 = t0 * wt4[0] + t1 * wt4[1] + t2 * wt4[2] + t3 * wt4[3];
        f4 a3 = t0 * t0 + t1 * t1 + t2 * t2 + t3 * t3;
        float s1 = qreduce((a1[0] + a1[1]) + (a1[2] + a1[3]));
        float s2 = qreduce((a2[0] + a2[1]) + (a2[2] + a2[3]));
        float s3 = qreduce((a3[0] + a3[1]) + (a3[2] + a3[3])) - x0 * x0;

        float A  = fmaf(kk, s1, -zeta * x0);
        float d0 = fmaf(zeta, x0 - s1, -th0);
        float m1 = s3 + nrm - 2.f * s2 + A * (2.f * (s1 - qd) + A * v2);
        float mkv = m1 - d0 * d0;
        if (p == 0) out[b * 256 + cand] = 0.85f - mkv + bhu + tanhf(btv);
    }
}

extern "C" void kernel_launch(void* const* d_in, const int* in_sizes, int n_in,
                              void* d_out, int out_size, void* d_ws, size_t ws_size,
                              hipStream_t stream) {
    const int*   pos = (const int*)d_in[0];
    const int*   neg = (const int*)d_in[1];
    const float* emb = (const float*)d_in[2];
    const float* bh  = (const float*)d_in[3];
    const float* bt  = (const float*)d_in[4];
    const float* rwh = (const float*)d_in[5];
    const float* bwh = (const float*)d_in[6];
    const float* rwt = (const float*)d_in[7];
    const float* bwt = (const float*)d_in[8];
    float* ws   = (float*)d_ws;
    float* wrog = ws + OFF_WRO;
    float* wthg = ws + OFF_WTH;
    float* thcg = ws + OFF_TC;
    float* zkg  = ws + OFF_ZK;
    float* out  = (float*)d_out;

    k_prep  <<<dim3(512),  dim3(512), 0, stream>>>(rwh, rwt, bwh, bwt, pos, emb,
                                                   bh, wrog, wthg, thcg, zkg);
    k3_score<<<dim3(1024), dim3(256), 0, stream>>>(pos, neg, emb, bt, wrog, wthg,
                                                   thcg, zkg, out);
}